// Round 11
// baseline (273.556 us; speedup 1.0000x reference)
//
#include <hip/hip_runtime.h>

#define N_NODES 100000
#define DIM 128
#define N_REL 8
#define N_EDGES 625000
#define RN 800000            // N_REL * N_NODES (keys r*N+d)
#define N_PADROWS 100032     // 3126 blocks * 32 rows
#define SCAN_BLOCKS 98
#define SCAN_CHUNK 8192      // 256 threads * 32 elems

// fp32 -> bf16, round-to-nearest-even
__device__ __forceinline__ unsigned short f2bf(float f) {
    unsigned int u = __float_as_uint(f);
    u += 0x7fffu + ((u >> 16) & 1u);
    return (unsigned short)(u >> 16);
}

__device__ __forceinline__ float bf2f(unsigned short s) {
    return __uint_as_float(((unsigned int)s) << 16);
}

// prep: x->bf16 (12.8M elems, 4/thread, exact grid), zero xb pad rows,
// W -> MFMA B-frag order, (rel,dst) histogram + per-edge rank (degi pre-zeroed).
__global__ __launch_bounds__(256) void prep_kernel(const float* __restrict__ x,
                                                   const float* __restrict__ relw,
                                                   const float* __restrict__ selfw,
                                                   const int* __restrict__ dst,
                                                   const int* __restrict__ rel,
                                                   unsigned short* __restrict__ xb,
                                                   unsigned short* __restrict__ Wt,
                                                   int* __restrict__ degi,
                                                   int* __restrict__ rank) {
    int i = blockIdx.x * 256 + threadIdx.x;      // 0 .. 3,199,999 exact
    {
        float4 v = *(const float4*)(x + (size_t)i * 4);
        unsigned short t[4] = {f2bf(v.x), f2bf(v.y), f2bf(v.z), f2bf(v.w)};
        *(uint2*)(xb + (size_t)i * 4) = *(const uint2*)t;
    }
    if (i < 512) {  // zero pad rows 100000..100031
        uint4 z = {0, 0, 0, 0};
        *(uint4*)(xb + (size_t)N_NODES * DIM + i * 8) = z;
    }
    if (i < 147456) {  // Wt[(((r*4+ks)*8+t)*64+lane)*8+j] = W_r[din=ks*32+quad*8+j][dout=t*16+m16]
        int j = i & 7;
        int lane = (i >> 3) & 63;
        int t = (i >> 9) & 7;
        int ks = (i >> 12) & 3;
        int r = i >> 14;
        int m16 = lane & 15, quad = lane >> 4;
        int din = ks * 32 + quad * 8 + j;
        int dout = t * 16 + m16;
        float v = (r < 8) ? relw[(r << 14) + (din << 7) + dout] : selfw[(din << 7) + dout];
        Wt[i] = f2bf(v);
    }
    if (i < N_EDGES) {
        // rank within (rel,dst) segment; removes the atomic pass from fill_kernel
        rank[i] = atomicAdd(&degi[rel[i] * N_NODES + dst[i]], 1);
    }
}

// Single-pass exclusive scan of degi[RN] -> offs, wave-parallel lookback.
// 98 blocks are all co-resident (<< 256 CUs) so spinning on blockIdx order is safe.
// status word: bit31=prefix-ready, bit30=aggregate-ready, low 30 bits = value.
__global__ __launch_bounds__(256) void scan_kernel(const int* __restrict__ degi,
                                                   unsigned int* __restrict__ status,
                                                   int* __restrict__ offs) {
    __shared__ int lsum[256];
    __shared__ int lpfx;
    const int tid = threadIdx.x;
    const int b = blockIdx.x;
    const int base = b * SCAN_CHUNK + tid * 32;
    int v[32];
    int s = 0;
#pragma unroll
    for (int j = 0; j < 8; j++) {
        int idx = base + j * 4;
        int4 d = {0, 0, 0, 0};
        if (idx + 3 < RN) d = *(const int4*)(degi + idx);
        else {
            if (idx < RN) d.x = degi[idx];
            if (idx + 1 < RN) d.y = degi[idx + 1];
            if (idx + 2 < RN) d.z = degi[idx + 2];
        }
        v[j * 4] = d.x; v[j * 4 + 1] = d.y; v[j * 4 + 2] = d.z; v[j * 4 + 3] = d.w;
        s += d.x + d.y + d.z + d.w;
    }
    lsum[tid] = s;
    __syncthreads();
    for (int off = 1; off < 256; off <<= 1) {
        int p = (tid >= off) ? lsum[tid - off] : 0;
        __syncthreads();
        lsum[tid] += p;
        __syncthreads();
    }
    int thrbase = lsum[tid] - s;
    int total = lsum[255];

    if (b == 0) {
        if (tid == 0) {
            atomicExch(&status[0], 0x80000000u | (unsigned)total);
            lpfx = 0;
        }
    } else {
        if (tid == 0) atomicExch(&status[b], 0x40000000u | (unsigned)total);
        if (tid < 64) {
            int sum = 0;
            int j = b - 1;
            while (true) {
                int idx = j - tid;
                unsigned st = (idx >= 0) ? atomicAdd(&status[idx], 0u) : 0x80000000u;
                unsigned long long pball = __ballot(st & 0x80000000u);
                unsigned long long zball = __ballot(st == 0u);
                int fp = pball ? (__ffsll(pball) - 1) : 64;
                unsigned long long below = (fp >= 64) ? ~0ull : ((1ull << fp) - 1ull);
                if (zball & below) continue;         // gap not ready yet, re-read
                int lim = (fp < 64) ? fp : 63;
                int val = (tid <= lim) ? (int)(st & 0x3fffffffu) : 0;
                for (int o = 32; o > 0; o >>= 1) val += __shfl_down(val, o);
                sum += __shfl(val, 0);
                if (fp < 64) break;
                j -= 64;
            }
            if (tid == 0) {
                atomicExch(&status[b], 0x80000000u | (unsigned)(sum + total));
                lpfx = sum;
            }
        }
    }
    __syncthreads();
    int run = lpfx + thrbase;
#pragma unroll
    for (int j = 0; j < 32; j++) {
        int idx = base + j;
        if (idx < RN) {
            offs[idx] = run;
            if (idx == RN - 1) offs[RN] = run + v[j];
            run += v[j];
        }
    }
}

// Bin edges by key r*N+d using precomputed rank (no atomics).
// slot word = src | (d&15)<<17 (deg = segment length).
__global__ __launch_bounds__(256) void fill_kernel(const int* __restrict__ src,
                                                   const int* __restrict__ dst,
                                                   const int* __restrict__ rel,
                                                   const int* __restrict__ rank,
                                                   const int* __restrict__ offs,
                                                   unsigned int* __restrict__ ebuf) {
    int e = blockIdx.x * 256 + threadIdx.x;
    if (e < N_EDGES) {
        int d = dst[e];
        int key = rel[e] * N_NODES + d;
        int pos = offs[key] + rank[e];
        ebuf[pos] = (unsigned int)src[e] | ((unsigned int)(d & 15) << 17);
    }
}

typedef __attribute__((ext_vector_type(8))) short frag8;
typedef __attribute__((ext_vector_type(4))) float f32x4;

// Fused aggregate+transform, COLUMN-SPLIT WAVE PAIRS (r9 design, resubmitted after
// infra-failed bench; kernel re-audited: uniform barriers, all indices in bounds):
//  block = 32 dst rows, 8 waves (512 thr): g=wave>>2 row-group (16 rows),
//  h=(wave>>1)&1 rel-half (rels h*4..h*4+3), c=wave&1 col-half (cols c*64..c*64+63).
//  The (g,h,0)/(g,h,1) pair shares two 4KB tiles TA/TB: per it in {0,1}, c0 gathers
//  rel h*4+2it into TA while c1 gathers h*4+2it+1 into TB (independent, r3's proven
//  gather core verbatim); barrier; BOTH waves MFMA BOTH tiles on their own col-half
//  (acc[4] = 16 regs, half of r3's 32); barrier; refill.
//  Why: the session-proven ~92-reg/wave budget was the occupancy blocker (r1/r4/r7
//  spilled when forced). Halving acc + halving per-wave work is the only lever that
//  RELIEVES the budget instead of fighting it: ~76-85 regs -> 4-6 waves/SIMD and
//  2x wave count, attacking the measured ~85% stall fraction directly.
//  Merge across h only (c-halves own disjoint columns); direct 64B-segment stores
//  (no LDS repack). 32KB LDS. launch_bounds(512,4): cap 128 regs (same as r3, safe).
__global__ __launch_bounds__(512, 4) void fused_kernel(const unsigned short* __restrict__ xb,
                                                       const unsigned short* __restrict__ Wt,
                                                       const int* __restrict__ offs2,
                                                       const unsigned int* __restrict__ ebuf,
                                                       const float* __restrict__ bias,
                                                       float* __restrict__ out) {
    __shared__ __align__(16) unsigned char ldsraw[32768];   // 4 pairs x (TA+TB)

    const int tid = threadIdx.x;
    const int wave = tid >> 6, lane = tid & 63;
    const int g = wave >> 2, h = (wave >> 1) & 1, c = wave & 1;
    const int m16 = lane & 15, quad = lane >> 4;
    const int dbase = blockIdx.x * 32 + g * 16;
    unsigned char* pairT = ldsraw + (g * 2 + h) * 8192;   // TA | TB of my pair
    unsigned char* myT = pairT + c * 4096;
    const unsigned int* xb32 = (const unsigned int*)xb;

    int cidx = dbase + lane;
    if (cidx > N_NODES) cidx = N_NODES;

    // my two gather relations: rA = h*4+c (it=0), rB = h*4+c+2 (it=1)
    int obA = offs2[(size_t)(h * 4 + c) * N_NODES + cidx];
    int obB = offs2[(size_t)(h * 4 + c + 2) * N_NODES + cidx];

    f32x4 acc[4];
#pragma unroll
    for (int t = 0; t < 4; t++) acc[t] = (f32x4){0.f, 0.f, 0.f, 0.f};

    int sA = __builtin_amdgcn_readlane(obA, 0);
    int cntA = __builtin_amdgcn_readlane(obA, 16) - sA;
    int sB = __builtin_amdgcn_readlane(obB, 0);
    int cntB = __builtin_amdgcn_readlane(obB, 16) - sB;
    unsigned int ewA = 0, ewB = 0;
    if (lane < cntA) ewA = ebuf[sA + lane];
    if (lane < cntB) ewB = ebuf[sB + lane];

    {   // ---- selfloop quarter: ks = h*2..h*2+1, cols c*64..: covers ew latency ----
        const unsigned short* ap = xb + (size_t)(dbase + m16) * DIM;
#pragma unroll
        for (int k2 = 0; k2 < 2; k2++) {
            int ks = h * 2 + k2;
            frag8 a = *(const frag8*)(ap + ks * 32 + quad * 8);
            const frag8* bp = (const frag8*)Wt + ((8 * 4 + ks) * 8 + c * 4) * 64 + lane;
#pragma unroll
            for (int t = 0; t < 4; t++)
                acc[t] = __builtin_amdgcn_mfma_f32_16x16x32_bf16(a, bp[t * 64], acc[t], 0, 0, 0);
        }
    }

    // preload first row-batch of my it=0 relation
    unsigned int u0[8], v0[8];
    if (cntA > 0) {
        int cl = cntA; if (cl > 64) cl = 64;
#pragma unroll
        for (int k = 0; k < 8; k++) {
            int li = k; if (li >= cl) li = cl - 1;
            u0[k] = (unsigned int)__builtin_amdgcn_readlane((int)ewA, li);
            v0[k] = xb32[(size_t)(u0[k] & 0x1ffffu) * 64 + lane];
        }
    }

    int s0 = sA, count = cntA;
    unsigned int ewc = ewA;

#pragma unroll 1
    for (int it = 0; it < 2; ++it) {
        // pre-zero my tile (empty segments stay zero)
        {
            uint4 z = {0, 0, 0, 0};
            *(uint4*)(myT + lane * 16) = z;
            *(uint4*)(myT + 1024 + lane * 16) = z;
            *(uint4*)(myT + 2048 + lane * 16) = z;
            *(uint4*)(myT + 3072 + lane * 16) = z;
        }

        if (count > 0) {
            float ax = 0.f, ay = 0.f;
            int cur = -1, cnt = 0;
#pragma unroll 1
            for (int b0 = 0; b0 < count; b0 += 64) {
                int cl = count - b0; if (cl > 64) cl = 64;
                unsigned int ew = ewc;
                if (b0 > 0) {            // rare (count>64): refill inline
                    ew = 0;
                    if (b0 + lane < count) ew = ebuf[s0 + b0 + lane];
#pragma unroll
                    for (int k = 0; k < 8; k++) {
                        int li = k; if (li >= cl) li = cl - 1;
                        u0[k] = (unsigned int)__builtin_amdgcn_readlane((int)ew, li);
                        v0[k] = xb32[(size_t)(u0[k] & 0x1ffffu) * 64 + lane];
                    }
                }
#pragma unroll 1
                for (int i = 0; i < cl; i += 8) {
                    // issue next batch while this one is processed
                    unsigned int u1[8], v1[8];
                    if (i + 8 < cl) {    // wave-uniform
#pragma unroll
                        for (int k = 0; k < 8; k++) {
                            int li = i + 8 + k; if (li >= cl) li = cl - 1;
                            u1[k] = (unsigned int)__builtin_amdgcn_readlane((int)ew, li);
                            v1[k] = xb32[(size_t)(u1[k] & 0x1ffffu) * 64 + lane];
                        }
                    }
                    int kk = cl - i; if (kk > 8) kk = 8;
#pragma unroll
                    for (int k = 0; k < 8; k++) {
                        if (k < kk) {                    // wave-uniform guard
                            int dl = (int)((u0[k] >> 17) & 15u);
                            if (dl != cur) {
                                if (cnt > 0) {
                                    float inv = __builtin_amdgcn_rcpf((float)cnt);
                                    unsigned int p = (unsigned int)f2bf(ax * inv) |
                                                     ((unsigned int)f2bf(ay * inv) << 16);
                                    int bb = (lane >> 2) ^ cur;
                                    *(unsigned int*)(myT + cur * 256 + bb * 16 + (lane & 3) * 4) = p;
                                }
                                cur = dl; ax = 0.f; ay = 0.f; cnt = 0;
                            }
                            ax += bf2f((unsigned short)(v0[k] & 0xffffu));
                            ay += bf2f((unsigned short)(v0[k] >> 16));
                            cnt++;
                        }
                    }
                    if (i + 8 < cl) {    // rotate (static indices only)
#pragma unroll
                        for (int k = 0; k < 8; k++) { u0[k] = u1[k]; v0[k] = v1[k]; }
                    }
                }
            }
            {   // final flush (cnt>0 since count>0)
                float inv = __builtin_amdgcn_rcpf((float)cnt);
                unsigned int p = (unsigned int)f2bf(ax * inv) |
                                 ((unsigned int)f2bf(ay * inv) << 16);
                int bb = (lane >> 2) ^ cur;
                *(unsigned int*)(myT + cur * 256 + bb * 16 + (lane & 3) * 4) = p;
            }
        }

        // preload my it=1 relation's first batch NOW (hides under the MFMA phase)
        if (it == 0 && cntB > 0) {
            int cl = cntB; if (cl > 64) cl = 64;
#pragma unroll
            for (int k = 0; k < 8; k++) {
                int li = k; if (li >= cl) li = cl - 1;
                u0[k] = (unsigned int)__builtin_amdgcn_readlane((int)ewB, li);
                v0[k] = xb32[(size_t)(u0[k] & 0x1ffffu) * 64 + lane];
            }
        }

        __syncthreads();    // both tiles of every pair ready

        // MFMA both tiles on my col-half: TA <-> rel h*4+2it, TB <-> h*4+2it+1
#pragma unroll
        for (int pt = 0; pt < 2; ++pt) {
            const unsigned char* T = pairT + pt * 4096;
            int rel = h * 4 + it * 2 + pt;
#pragma unroll
            for (int ks = 0; ks < 4; ks++) {
                int bb = (4 * ks + quad) ^ m16;
                frag8 a = *(const frag8*)(T + m16 * 256 + bb * 16);
                const frag8* bp = (const frag8*)Wt + ((rel * 4 + ks) * 8 + c * 4) * 64 + lane;
#pragma unroll
                for (int t = 0; t < 4; t++)
                    acc[t] = __builtin_amdgcn_mfma_f32_16x16x32_bf16(a, bp[t * 64], acc[t], 0, 0, 0);
            }
        }

        __syncthreads();    // tiles consumed by both waves; safe to refill

        // rotate relation state (scalars only)
        s0 = sB; count = cntB; ewc = ewB;
    }

    // ---- merge across h (c-halves are disjoint columns -> no c-merge) ----
    float* mbuf = (float*)(ldsraw + (g * 2 + c) * 4096);   // tiles free after loop barrier
    if (h == 1) {
#pragma unroll
        for (int t = 0; t < 4; t++)
            *(f32x4*)(mbuf + (t * 64 + lane) * 4) = acc[t];
    }
    __syncthreads();
    if (h == 0) {
#pragma unroll
        for (int t = 0; t < 4; t++) {
            f32x4 m = *(f32x4*)(mbuf + (t * 64 + lane) * 4);
            acc[t] += m;
        }
        // direct stores: elem (row = quad*4+i, col = c*64 + t*16 + m16);
        // each instr = 4 x 64B segments (rows) -- L2 merges; no LDS repack needed
#pragma unroll
        for (int t = 0; t < 4; t++) {
            float bc = bias[c * 64 + t * 16 + m16];
#pragma unroll
            for (int i = 0; i < 4; i++) {
                int gr = dbase + quad * 4 + i;
                if (gr < N_NODES)
                    out[(size_t)gr * DIM + c * 64 + t * 16 + m16] = acc[t][i] + bc;
            }
        }
    }
}

extern "C" void kernel_launch(void* const* d_in, const int* in_sizes, int n_in,
                              void* d_out, int out_size, void* d_ws, size_t ws_size,
                              hipStream_t stream) {
    const float* x = (const float*)d_in[0];
    const int* edge_index = (const int*)d_in[1]; // [2][E]: src then dst
    const int* edge_type = (const int*)d_in[2];
    const float* relw = (const float*)d_in[3];
    const float* selfw = (const float*)d_in[4];
    const float* bias = (const float*)d_in[5];
    float* out = (float*)d_out;
    (void)in_sizes; (void)n_in; (void)out_size; (void)ws_size;

    // ws: xb 25.6MB | Wt 0.29MB | offs2 3.2MB | ebuf 2.5MB
    char* ws = (char*)d_ws;
    size_t off = 0;
    unsigned short* xb = (unsigned short*)(ws + off); off += (size_t)N_PADROWS * DIM * 2;
    unsigned short* Wt = (unsigned short*)(ws + off); off += (size_t)9 * DIM * DIM * 2;
    int* offs2 = (int*)(ws + off); off += (size_t)(RN + 4) * 4;
    unsigned int* ebuf = (unsigned int*)(ws + off); off += (size_t)N_EDGES * 4;

    // pre-fused scratch in d_out (fused_kernel overwrites all of out at the end):
    // degi[RN] | status[SCAN_BLOCKS+2] | rank[N_EDGES]  (total ~5.7MB << 51.2MB)
    int* degi = (int*)d_out;
    unsigned int* status = (unsigned int*)(degi + RN);
    int* rank = (int*)(status + SCAN_BLOCKS + 2);

    const int* src = edge_index;
    const int* dst = edge_index + N_EDGES;

    hipMemsetAsync(degi, 0, (size_t)RN * 4 + (SCAN_BLOCKS + 2) * 4, stream);
    prep_kernel<<<12500, 256, 0, stream>>>(x, relw, selfw, dst, edge_type, xb, Wt, degi, rank);
    scan_kernel<<<SCAN_BLOCKS, 256, 0, stream>>>(degi, status, offs2);
    fill_kernel<<<(N_EDGES + 255) / 256, 256, 0, stream>>>(src, dst, edge_type, rank, offs2, ebuf);
    fused_kernel<<<N_PADROWS / 32, 512, 0, stream>>>(xb, Wt, offs2, ebuf, bias, out);
}

// Round 12
// 250.246 us; speedup vs baseline: 1.0931x; 1.0931x over previous
//
#include <hip/hip_runtime.h>

#define N_NODES 100000
#define DIM 128
#define N_REL 8
#define N_EDGES 625000
#define RN 800000            // N_REL * N_NODES (keys r*N+d)
#define N_PADROWS 100032     // 3126 blocks * 32 rows
#define SCAN_BLOCKS 98
#define SCAN_CHUNK 8192      // 256 threads * 32 elems

// fp32 -> bf16, round-to-nearest-even
__device__ __forceinline__ unsigned short f2bf(float f) {
    unsigned int u = __float_as_uint(f);
    u += 0x7fffu + ((u >> 16) & 1u);
    return (unsigned short)(u >> 16);
}

__device__ __forceinline__ float bf2f(unsigned short s) {
    return __uint_as_float(((unsigned int)s) << 16);
}

// prep: x->bf16 (12.8M elems, 4/thread, exact grid), zero xb pad rows,
// W -> MFMA B-frag order, (rel,dst) histogram + per-edge rank (degi pre-zeroed).
__global__ __launch_bounds__(256) void prep_kernel(const float* __restrict__ x,
                                                   const float* __restrict__ relw,
                                                   const float* __restrict__ selfw,
                                                   const int* __restrict__ dst,
                                                   const int* __restrict__ rel,
                                                   unsigned short* __restrict__ xb,
                                                   unsigned short* __restrict__ Wt,
                                                   int* __restrict__ degi,
                                                   int* __restrict__ rank) {
    int i = blockIdx.x * 256 + threadIdx.x;      // 0 .. 3,199,999 exact
    {
        float4 v = *(const float4*)(x + (size_t)i * 4);
        unsigned short t[4] = {f2bf(v.x), f2bf(v.y), f2bf(v.z), f2bf(v.w)};
        *(uint2*)(xb + (size_t)i * 4) = *(const uint2*)t;
    }
    if (i < 512) {  // zero pad rows 100000..100031
        uint4 z = {0, 0, 0, 0};
        *(uint4*)(xb + (size_t)N_NODES * DIM + i * 8) = z;
    }
    if (i < 147456) {  // Wt[(((r*4+ks)*8+t)*64+lane)*8+j] = W_r[din=ks*32+quad*8+j][dout=t*16+m16]
        int j = i & 7;
        int lane = (i >> 3) & 63;
        int t = (i >> 9) & 7;
        int ks = (i >> 12) & 3;
        int r = i >> 14;
        int m16 = lane & 15, quad = lane >> 4;
        int din = ks * 32 + quad * 8 + j;
        int dout = t * 16 + m16;
        float v = (r < 8) ? relw[(r << 14) + (din << 7) + dout] : selfw[(din << 7) + dout];
        Wt[i] = f2bf(v);
    }
    if (i < N_EDGES) {
        // rank within (rel,dst) segment; removes the atomic pass from fill_kernel
        rank[i] = atomicAdd(&degi[rel[i] * N_NODES + dst[i]], 1);
    }
}

// Single-pass exclusive scan of degi[RN] -> offs, wave-parallel lookback.
// 98 blocks are all co-resident (<< 256 CUs) so spinning on blockIdx order is safe.
// status word: bit31=prefix-ready, bit30=aggregate-ready, low 30 bits = value.
__global__ __launch_bounds__(256) void scan_kernel(const int* __restrict__ degi,
                                                   unsigned int* __restrict__ status,
                                                   int* __restrict__ offs) {
    __shared__ int lsum[256];
    __shared__ int lpfx;
    const int tid = threadIdx.x;
    const int b = blockIdx.x;
    const int base = b * SCAN_CHUNK + tid * 32;
    int v[32];
    int s = 0;
#pragma unroll
    for (int j = 0; j < 8; j++) {
        int idx = base + j * 4;
        int4 d = {0, 0, 0, 0};
        if (idx + 3 < RN) d = *(const int4*)(degi + idx);
        else {
            if (idx < RN) d.x = degi[idx];
            if (idx + 1 < RN) d.y = degi[idx + 1];
            if (idx + 2 < RN) d.z = degi[idx + 2];
        }
        v[j * 4] = d.x; v[j * 4 + 1] = d.y; v[j * 4 + 2] = d.z; v[j * 4 + 3] = d.w;
        s += d.x + d.y + d.z + d.w;
    }
    lsum[tid] = s;
    __syncthreads();
    for (int off = 1; off < 256; off <<= 1) {
        int p = (tid >= off) ? lsum[tid - off] : 0;
        __syncthreads();
        lsum[tid] += p;
        __syncthreads();
    }
    int thrbase = lsum[tid] - s;
    int total = lsum[255];

    if (b == 0) {
        if (tid == 0) {
            atomicExch(&status[0], 0x80000000u | (unsigned)total);
            lpfx = 0;
        }
    } else {
        if (tid == 0) atomicExch(&status[b], 0x40000000u | (unsigned)total);
        if (tid < 64) {
            int sum = 0;
            int j = b - 1;
            while (true) {
                int idx = j - tid;
                unsigned st = (idx >= 0) ? atomicAdd(&status[idx], 0u) : 0x80000000u;
                unsigned long long pball = __ballot(st & 0x80000000u);
                unsigned long long zball = __ballot(st == 0u);
                int fp = pball ? (__ffsll(pball) - 1) : 64;
                unsigned long long below = (fp >= 64) ? ~0ull : ((1ull << fp) - 1ull);
                if (zball & below) continue;         // gap not ready yet, re-read
                int lim = (fp < 64) ? fp : 63;
                int val = (tid <= lim) ? (int)(st & 0x3fffffffu) : 0;
                for (int o = 32; o > 0; o >>= 1) val += __shfl_down(val, o);
                sum += __shfl(val, 0);
                if (fp < 64) break;
                j -= 64;
            }
            if (tid == 0) {
                atomicExch(&status[b], 0x80000000u | (unsigned)(sum + total));
                lpfx = sum;
            }
        }
    }
    __syncthreads();
    int run = lpfx + thrbase;
#pragma unroll
    for (int j = 0; j < 32; j++) {
        int idx = base + j;
        if (idx < RN) {
            offs[idx] = run;
            if (idx == RN - 1) offs[RN] = run + v[j];
            run += v[j];
        }
    }
}

// Bin edges by key r*N+d using precomputed rank (no atomics).
// slot word = src | (d&15)<<17 (deg = segment length).
__global__ __launch_bounds__(256) void fill_kernel(const int* __restrict__ src,
                                                   const int* __restrict__ dst,
                                                   const int* __restrict__ rel,
                                                   const int* __restrict__ rank,
                                                   const int* __restrict__ offs,
                                                   unsigned int* __restrict__ ebuf) {
    int e = blockIdx.x * 256 + threadIdx.x;
    if (e < N_EDGES) {
        int d = dst[e];
        int key = rel[e] * N_NODES + d;
        int pos = offs[key] + rank[e];
        ebuf[pos] = (unsigned int)src[e] | ((unsigned int)(d & 15) << 17);
    }
}

typedef __attribute__((ext_vector_type(8))) short frag8;
typedef __attribute__((ext_vector_type(4))) float f32x4;

// Fused aggregate+transform == round-3's verified 105us kernel with ONE change:
//  16-DEEP row-load batches (u0/v0[16]) replacing 8-deep + 1-ahead (u0/u1/v0/v1).
//  Register-neutral (32 regs either way). Why: per relation (lambda=12.5 edges),
//  batch0 was hidden under the previous MFMA but batch1 (edges 8..15) stalled
//  ~400-500cy behind only ~100cy of processing, and P(count>8)=0.86. One 16-deep
//  preloaded burst covers 86% of segments entirely (P(count<=16)=0.87); count>16
//  refills inline (13%, amortized). Also doubles outstanding loads per burst.
//  r9's setprio + selfloop-split are dropped (measured duds: fused 105->111).
//  Everything else r3-identical: block = 32 dst rows, 4 waves (g=row-group,
//  h=rel-group), offs 2 rels ahead, edge words 1 rel ahead, first batch of r+1
//  issued before r's MFMA, 16KB LDS, launch_bounds(256,4).
__global__ __launch_bounds__(256, 4) void fused_kernel(const unsigned short* __restrict__ xb,
                                                       const unsigned short* __restrict__ Wt,
                                                       const int* __restrict__ offs2,
                                                       const unsigned int* __restrict__ ebuf,
                                                       const float* __restrict__ bias,
                                                       float* __restrict__ out) {
    __shared__ __align__(16) unsigned char ldsraw[16384];

    const int tid = threadIdx.x;
    const int wave = tid >> 6, lane = tid & 63;
    const int g = wave >> 1, h = wave & 1;
    const int m16 = lane & 15, quad = lane >> 4;
    const int dbase = blockIdx.x * 32 + g * 16;
    unsigned char* slab = ldsraw + wave * 4096;
    const unsigned int* xb32 = (const unsigned int*)xb;

    int cidx = dbase + lane;
    if (cidx > N_NODES) cidx = N_NODES;
    const int* obase = offs2 + (size_t)h * 4 * N_NODES + cidx;

    // descriptors for this wave's first two relations, issued up-front
    int obc = obase[0];
    int obn = obase[N_NODES];

    f32x4 acc[8];
#pragma unroll
    for (int t = 0; t < 8; t++) acc[t] = (f32x4){0.f, 0.f, 0.f, 0.f};

    // relation-0 state + edge-word prefetch (issue before selfloop so it arrives under it)
    int s0 = __builtin_amdgcn_readlane(obc, 0);
    int count = __builtin_amdgcn_readlane(obc, 16) - s0;
    unsigned int ewc = 0;
    if (lane < count) ewc = ebuf[s0 + lane];

    if (h == 0) {
        // ---- selfloop: A-frags direct from xb (pad rows zeroed); hides ew latency ----
        const unsigned short* ap = xb + (size_t)(dbase + m16) * DIM;
#pragma unroll
        for (int ks = 0; ks < 4; ks++) {
            frag8 a = *(const frag8*)(ap + ks * 32 + quad * 8);
            const frag8* bp = (const frag8*)Wt + ((8 * 4 + ks) * 8) * 64 + lane;
#pragma unroll
            for (int t = 0; t < 8; t++)
                acc[t] = __builtin_amdgcn_mfma_f32_16x16x32_bf16(a, bp[t * 64], acc[t], 0, 0, 0);
        }
    }

    // preload relation 0's first 16-deep row batch
    unsigned int u0[16], v0[16];
    if (count > 0) {
        int cl = count; if (cl > 64) cl = 64;
#pragma unroll
        for (int k = 0; k < 16; k++) {
            int li = k; if (li >= cl) li = cl - 1;
            u0[k] = (unsigned int)__builtin_amdgcn_readlane((int)ewc, li);
            v0[k] = xb32[(size_t)(u0[k] & 0x1ffffu) * 64 + lane];
        }
    }

#pragma unroll 1
    for (int r = 0; r < 4; r++) {
        // prefetch chain: r+1 edge words (offs already resident), r+2 offs
        int s0n = __builtin_amdgcn_readlane(obn, 0);
        int cntn = __builtin_amdgcn_readlane(obn, 16) - s0n;
        unsigned int ewn = 0;
        if (r < 3 && lane < cntn) ewn = ebuf[s0n + lane];
        int obn2 = (r < 2) ? obase[(r + 2) * N_NODES] : 0;

        // pre-zero the 4KB tile (empty segments stay zero)
        {
            uint4 z = {0, 0, 0, 0};
            *(uint4*)(slab + lane * 16) = z;
            *(uint4*)(slab + 1024 + lane * 16) = z;
            *(uint4*)(slab + 2048 + lane * 16) = z;
            *(uint4*)(slab + 3072 + lane * 16) = z;
        }

        if (count > 0) {
            float ax = 0.f, ay = 0.f;
            int cur = -1, cnt = 0;
#pragma unroll 1
            for (int b0 = 0; b0 < count; b0 += 64) {
                int cl = count - b0; if (cl > 64) cl = 64;
                unsigned int ew = ewc;
                if (b0 > 0) {            // rare (count>64): refill edge words inline
                    ew = 0;
                    if (b0 + lane < count) ew = ebuf[s0 + b0 + lane];
                }
#pragma unroll 1
                for (int i = 0; i < cl; i += 16) {
                    if (b0 + i > 0) {    // refill batch inline (13% of segments)
#pragma unroll
                        for (int k = 0; k < 16; k++) {
                            int li = i + k; if (li >= cl) li = cl - 1;
                            u0[k] = (unsigned int)__builtin_amdgcn_readlane((int)ew, li);
                            v0[k] = xb32[(size_t)(u0[k] & 0x1ffffu) * 64 + lane];
                        }
                    }
                    int kk = cl - i; if (kk > 16) kk = 16;
#pragma unroll
                    for (int k = 0; k < 16; k++) {
                        if (k < kk) {                    // wave-uniform guard
                            int dl = (int)((u0[k] >> 17) & 15u);
                            if (dl != cur) {
                                if (cnt > 0) {
                                    float inv = __builtin_amdgcn_rcpf((float)cnt);
                                    unsigned int p = (unsigned int)f2bf(ax * inv) |
                                                     ((unsigned int)f2bf(ay * inv) << 16);
                                    int bb = (lane >> 2) ^ cur;
                                    *(unsigned int*)(slab + cur * 256 + bb * 16 + (lane & 3) * 4) = p;
                                }
                                cur = dl; ax = 0.f; ay = 0.f; cnt = 0;
                            }
                            ax += bf2f((unsigned short)(v0[k] & 0xffffu));
                            ay += bf2f((unsigned short)(v0[k] >> 16));
                            cnt++;
                        }
                    }
                }
            }
            {   // final flush (cnt>0 since count>0)
                float inv = __builtin_amdgcn_rcpf((float)cnt);
                unsigned int p = (unsigned int)f2bf(ax * inv) |
                                 ((unsigned int)f2bf(ay * inv) << 16);
                int bb = (lane >> 2) ^ cur;
                *(unsigned int*)(slab + cur * 256 + bb * 16 + (lane & 3) * 4) = p;
            }
        }

        // preload r+1's first 16-deep batch NOW so its latency hides under the MFMA
        if (r < 3 && cntn > 0) {
            int cl = cntn; if (cl > 64) cl = 64;
#pragma unroll
            for (int k = 0; k < 16; k++) {
                int li = k; if (li >= cl) li = cl - 1;
                u0[k] = (unsigned int)__builtin_amdgcn_readlane((int)ewn, li);
                v0[k] = xb32[(size_t)(u0[k] & 0x1ffffu) * 64 + lane];
            }
        }

        // A-frags from swizzled tile + MFMA (LDS ops in-order per wave; no barrier)
#pragma unroll
        for (int ks = 0; ks < 4; ks++) {
            int bb = (4 * ks + quad) ^ m16;
            frag8 a = *(const frag8*)(slab + m16 * 256 + bb * 16);
            const frag8* bp = (const frag8*)Wt + (((h * 4 + r) * 4 + ks) * 8) * 64 + lane;
#pragma unroll
            for (int t = 0; t < 8; t++)
                acc[t] = __builtin_amdgcn_mfma_f32_16x16x32_bf16(a, bp[t * 64], acc[t], 0, 0, 0);
        }

        // rotate relation state
        s0 = s0n; count = cntn; ewc = ewn; obn = obn2;
    }

    // ---- merge rel-halves: h=1 waves publish acc via LDS (reusing gather slabs) ----
    __syncthreads();
    unsigned char* mbuf = ldsraw + g * 8192;
    if (h == 1) {
#pragma unroll
        for (int t = 0; t < 8; t++)
            *(f32x4*)(mbuf + (t * 64 + lane) * 16) = acc[t];
    }
    __syncthreads();
    if (h == 0) {
#pragma unroll
        for (int t = 0; t < 8; t++) {
            f32x4 m = *(f32x4*)(mbuf + (t * 64 + lane) * 16);
            acc[t] += m;
        }

        // ---- epilogue: +bias, two column-halves through mbuf (wave-private now;
        // own reads above are LDS-ordered before these writes)
        float* S = (float*)mbuf;
#pragma unroll
        for (int hh = 0; hh < 2; hh++) {
#pragma unroll
            for (int tt = 0; tt < 4; tt++) {
                int t = hh * 4 + tt;
                float bc = bias[t * 16 + m16];
#pragma unroll
                for (int i = 0; i < 4; i++)
                    S[(quad * 4 + i) * 68 + tt * 16 + m16] = acc[t][i] + bc;
            }
#pragma unroll
            for (int c = 0; c < 4; c++) {
                int row16 = c * 4 + quad;
                int gr = dbase + row16;
                if (gr < N_NODES)
                    *(float4*)(out + (size_t)gr * DIM + hh * 64 + m16 * 4) =
                        *(float4*)(S + row16 * 68 + m16 * 4);
            }
        }
    }
}

extern "C" void kernel_launch(void* const* d_in, const int* in_sizes, int n_in,
                              void* d_out, int out_size, void* d_ws, size_t ws_size,
                              hipStream_t stream) {
    const float* x = (const float*)d_in[0];
    const int* edge_index = (const int*)d_in[1]; // [2][E]: src then dst
    const int* edge_type = (const int*)d_in[2];
    const float* relw = (const float*)d_in[3];
    const float* selfw = (const float*)d_in[4];
    const float* bias = (const float*)d_in[5];
    float* out = (float*)d_out;
    (void)in_sizes; (void)n_in; (void)out_size; (void)ws_size;

    // ws: xb 25.6MB | Wt 0.29MB | offs2 3.2MB | ebuf 2.5MB
    char* ws = (char*)d_ws;
    size_t off = 0;
    unsigned short* xb = (unsigned short*)(ws + off); off += (size_t)N_PADROWS * DIM * 2;
    unsigned short* Wt = (unsigned short*)(ws + off); off += (size_t)9 * DIM * DIM * 2;
    int* offs2 = (int*)(ws + off); off += (size_t)(RN + 4) * 4;
    unsigned int* ebuf = (unsigned int*)(ws + off); off += (size_t)N_EDGES * 4;

    // pre-fused scratch in d_out (fused_kernel overwrites all of out at the end):
    // degi[RN] | status[SCAN_BLOCKS+2] | rank[N_EDGES]  (total ~5.7MB << 51.2MB)
    int* degi = (int*)d_out;
    unsigned int* status = (unsigned int*)(degi + RN);
    int* rank = (int*)(status + SCAN_BLOCKS + 2);

    const int* src = edge_index;
    const int* dst = edge_index + N_EDGES;

    hipMemsetAsync(degi, 0, (size_t)RN * 4 + (SCAN_BLOCKS + 2) * 4, stream);
    prep_kernel<<<12500, 256, 0, stream>>>(x, relw, selfw, dst, edge_type, xb, Wt, degi, rank);
    scan_kernel<<<SCAN_BLOCKS, 256, 0, stream>>>(degi, status, offs2);
    fill_kernel<<<(N_EDGES + 255) / 256, 256, 0, stream>>>(src, dst, edge_type, rank, offs2, ebuf);
    fused_kernel<<<N_PADROWS / 32, 256, 0, stream>>>(xb, Wt, offs2, ebuf, bias, out);
}